// Round 8
// baseline (28.829 us; speedup 1.0000x reference)
//
#include <hip/hip_runtime.h>

#define HW_TOT (2048 * 2048)
#define KLAB 32
#define NLAB 16
#define NBIN (NLAB * KLAB)   // 512
#define NREP 32              // replicated global histograms / ticket groups
#define NBLK 1024            // grid
#define GRPSZ (NBLK / NREP)  // 32 blocks per ticket group

typedef int   vint4   __attribute__((ext_vector_type(4)));
typedef float vfloat4 __attribute__((ext_vector_type(4)));

// ws layout (memset zeroes first 65792 bytes each call):
//   [0)        u32 hist2[NREP*NBIN]   65536 B
//   [65536)    u32 gticket[32]          128 B
//   [65664)    u32 fticket                4 B   (+pad to 256)
//   [65792)    u32 parts[NBLK*4]      16384 B   (atomicExch-written every call)

__global__ __launch_bounds__(256) void connect_fused(
    const vint4* __restrict__ pim, const vfloat4* __restrict__ ps,
    const vfloat4* __restrict__ co, const vint4* __restrict__ tm,
    unsigned int* __restrict__ hist2, unsigned int* __restrict__ gticket,
    unsigned int* __restrict__ fticket, unsigned int* __restrict__ parts,
    float* __restrict__ out, int nvec)
{
    __shared__ unsigned int lh[NBIN];
    __shared__ float red[4][4];
    __shared__ int   isLast;

    for (int i = threadIdx.x; i < NBIN; i += 256) lh[i] = 0u;
    __syncthreads();

    float s2 = 0.f, sp = 0.f, spt = 0.f, sbce = 0.f;

    const int stride = gridDim.x * blockDim.x;
    for (int i = blockIdx.x * blockDim.x + threadIdx.x; i < nvec; i += stride) {
        vint4   pv = __builtin_nontemporal_load(&pim[i]);
        vfloat4 sv = __builtin_nontemporal_load(&ps[i]);
        vfloat4 cv = __builtin_nontemporal_load(&co[i]);
        vint4   tv = __builtin_nontemporal_load(&tm[i]);

#pragma unroll
        for (int e = 0; e < 4; ++e) {
            float s = sv[e];
            float p = cv[e];
            int   t = tv[e];
            int   k = pv[e];

            s2 += s * s;
            sp += p;
            bool tb = (t > 0);
            float sel = tb ? p : (1.0f - p);
            float lg = fmaxf(__logf(sel), -100.0f);
            sbce += lg;
            if (tb) spt += p;

            atomicAdd(&lh[t * KLAB + k], 1u);
        }
    }

    // wave-level reduce of scalar partials
#pragma unroll
    for (int off = 32; off > 0; off >>= 1) {
        s2   += __shfl_down(s2, off);
        sp   += __shfl_down(sp, off);
        spt  += __shfl_down(spt, off);
        sbce += __shfl_down(sbce, off);
    }
    int wave = threadIdx.x >> 6;
    if ((threadIdx.x & 63) == 0) {
        red[wave][0] = s2; red[wave][1] = sp; red[wave][2] = spt; red[wave][3] = sbce;
    }
    __syncthreads();  // red written AND all LDS histogram atomics complete

    if (threadIdx.x == 0) {
        // per-block scalars -> device-scope atomicExch (coherent, no plain store)
        float r0 = red[0][0] + red[1][0] + red[2][0] + red[3][0];
        float r1 = red[0][1] + red[1][1] + red[2][1] + red[3][1];
        float r2 = red[0][2] + red[1][2] + red[2][2] + red[3][2];
        float r3 = red[0][3] + red[1][3] + red[2][3] + red[3][3];
        unsigned int* row = parts + blockIdx.x * 4;
        atomicExch(&row[0], __float_as_uint(r0));
        atomicExch(&row[1], __float_as_uint(r1));
        atomicExch(&row[2], __float_as_uint(r2));
        atomicExch(&row[3], __float_as_uint(r3));
    }

    // flush LDS histogram into one of NREP replicas
    unsigned int* rep = hist2 + (blockIdx.x & (NREP - 1)) * NBIN;
    for (int i = threadIdx.x; i < NBIN; i += 256) {
        unsigned int v = lh[i];
        if (v) atomicAdd(&rep[i], v);
    }

    // ---- release: each thread waits for its own atomics to be acked (cheap,
    // no cache-maintenance), then block-wide barrier ----
    asm volatile("s_waitcnt vmcnt(0)" ::: "memory");
    __syncthreads();

    // ---- hierarchical completion tickets: max 32 adds per address ----
    if (threadIdx.x == 0) {
        int last = 0;
        unsigned int o = atomicAdd(&gticket[blockIdx.x & (NREP - 1)], 1u);
        if (o == GRPSZ - 1) {                       // last block of this group
            unsigned int o2 = atomicAdd(fticket, 1u);
            last = (o2 == NREP - 1);                // last group overall
        }
        isLast = last;
    }
    __syncthreads();
    if (!isLast) return;
    __threadfence();  // single acquire fence: invalidate stale cached lines

    // ---- finalize with 256 threads (2 bins/thread) — validated in R6 ----
    __shared__ float  fh[NBIN];
    __shared__ double sred[4][4];
    __shared__ float  rowmin[NLAB];
    __shared__ float  strow[NLAB];

    int tid = threadIdx.x;

    unsigned int h0 = 0u, h1 = 0u;
#pragma unroll
    for (int c = 0; c < NREP; ++c) {
        h0 += hist2[c * NBIN + tid];
        h1 += hist2[c * NBIN + tid + 256];
    }
    fh[tid]       = (float)h0;
    fh[tid + 256] = (float)h1;

    const float4* pf = (const float4*)parts;
    double d2 = 0.0, dp = 0.0, dpt = 0.0, dbce = 0.0;
#pragma unroll
    for (int b = 0; b < NBLK / 256; ++b) {
        float4 r = pf[tid + b * 256];
        d2 += r.x; dp += r.y; dpt += r.z; dbce += r.w;
    }
#pragma unroll
    for (int off = 32; off > 0; off >>= 1) {
        d2   += __shfl_down(d2, off);
        dp   += __shfl_down(dp, off);
        dpt  += __shfl_down(dpt, off);
        dbce += __shfl_down(dbce, off);
    }
    if ((tid & 63) == 0) {
        int w = tid >> 6;
        sred[w][0] = d2; sred[w][1] = dp; sred[w][2] = dpt; sred[w][3] = dbce;
    }
    __syncthreads();

    int n0 = tid >> 5;        // rows 0..7
    int n1 = n0 + 8;          // rows 8..15
    int k  = tid & 31;

    float st0 = 0.f, st1 = 0.f, spk = 0.f;
#pragma unroll
    for (int kk = 0; kk < KLAB; ++kk) {
        st0 += fh[n0 * KLAB + kk];
        st1 += fh[n1 * KLAB + kk];
    }
#pragma unroll
    for (int nn = 0; nn < NLAB; ++nn) spk += fh[nn * KLAB + k];

    float I0 = fh[n0 * KLAB + k], I1 = fh[n1 * KLAB + k];
    float u0 = st0 + spk,         u1 = st1 + spk;
    float pair0 = 100.0f * (u0 - 2.0f * I0) / (float)HW_TOT
                + 1.0f - (2.0f * I0 + 1.0f) / (u0 + 1.0f);
    float pair1 = 100.0f * (u1 - 2.0f * I1) / (float)HW_TOT
                + 1.0f - (2.0f * I1 + 1.0f) / (u1 + 1.0f);

#pragma unroll
    for (int off = 16; off > 0; off >>= 1) {
        pair0 = fminf(pair0, __shfl_xor(pair0, off));
        pair1 = fminf(pair1, __shfl_xor(pair1, off));
    }
    if (k == 0) {
        rowmin[n0] = pair0; strow[n0] = st0;
        rowmin[n1] = pair1; strow[n1] = st1;
    }
    __syncthreads();

    if (tid == 0) {
        double S2 = 0, SP = 0, SPT = 0, SBCE = 0;
#pragma unroll
        for (int w = 0; w < 4; ++w) {
            S2 += sred[w][0]; SP += sred[w][1]; SPT += sred[w][2]; SBCE += sred[w][3];
        }
        double hw = (double)HW_TOT;
        double res = S2 / hw;                 // MSE(pred_score, 0)
        res += -SBCE / hw;                    // BCE(cls_out, t)
        double sum_t = hw - (double)strow[0]; // count(target > 0)
        res += 1.0 - (2.0 * SPT + 1.0) / (SP + sum_t + 1.0);
        float pm = 0.f;
#pragma unroll
        for (int i = 0; i < NLAB; ++i) pm += rowmin[i];
        res += (double)pm;
        out[0] = (float)(res / (double)NLAB);
    }
}

extern "C" void kernel_launch(void* const* d_in, const int* in_sizes, int n_in,
                              void* d_out, int out_size, void* d_ws, size_t ws_size,
                              hipStream_t stream) {
    const vint4*   pim = (const vint4*)d_in[0];
    const vfloat4* ps  = (const vfloat4*)d_in[1];
    const vfloat4* co  = (const vfloat4*)d_in[2];
    const vint4*   tm  = (const vint4*)d_in[3];
    float* out = (float*)d_out;

    char* base = (char*)d_ws;
    unsigned int* hist2   = (unsigned int*)base;                 // 65536 B
    unsigned int* gticket = (unsigned int*)(base + 65536);       // 128 B
    unsigned int* fticket = (unsigned int*)(base + 65664);       // 4 B
    unsigned int* parts   = (unsigned int*)(base + 65792);       // 16384 B

    (void)hipMemsetAsync(d_ws, 0, 65792, stream);

    const int nvec = HW_TOT / 4;
    connect_fused<<<NBLK, 256, 0, stream>>>(pim, ps, co, tm, hist2, gticket,
                                            fticket, parts, out, nvec);
}

// Round 9
// 25.346 us; speedup vs baseline: 1.1374x; 1.1374x over previous
//
#include <hip/hip_runtime.h>

#define HW_TOT (2048 * 2048)
#define KLAB 32
#define NLAB 16
#define NBIN (NLAB * KLAB)   // 512
#define NBLK 512             // k1 grid: 2 blocks/CU, 8 waves each
#define BTHR 512             // threads per k1 block

typedef int   vint4   __attribute__((ext_vector_type(4)));
typedef float vfloat4 __attribute__((ext_vector_type(4)));

// ws layout (every byte store-overwritten each call -> no memset needed):
//   [0)       u32 hist1[NBLK][NBIN/2]   512 KB  (packed u16 pairs: bins 2i,2i+1)
//   [524288)  float4 parts[NBLK]          8 KB

__global__ __launch_bounds__(BTHR) void connect_k1(
    const vint4* __restrict__ pim, const vfloat4* __restrict__ ps,
    const vfloat4* __restrict__ co, const vint4* __restrict__ tm,
    float4* __restrict__ parts, unsigned int* __restrict__ hist1, int nvec)
{
    __shared__ unsigned int lh[NBIN];
    __shared__ float red[8][4];

    lh[threadIdx.x] = 0u;  // 512 threads, 512 bins
    __syncthreads();

    float s2 = 0.f, sp = 0.f, spt = 0.f, sbce = 0.f;

    const int stride = gridDim.x * blockDim.x;
    for (int i = blockIdx.x * blockDim.x + threadIdx.x; i < nvec; i += stride) {
        vint4   pv = __builtin_nontemporal_load(&pim[i]);
        vfloat4 sv = __builtin_nontemporal_load(&ps[i]);
        vfloat4 cv = __builtin_nontemporal_load(&co[i]);
        vint4   tv = __builtin_nontemporal_load(&tm[i]);

#pragma unroll
        for (int e = 0; e < 4; ++e) {
            float s = sv[e];
            float p = cv[e];
            int   t = tv[e];
            int   k = pv[e];

            s2 += s * s;
            sp += p;
            bool tb = (t > 0);
            float sel = tb ? p : (1.0f - p);
            float lg = fmaxf(__logf(sel), -100.0f);
            sbce += lg;
            if (tb) spt += p;

            atomicAdd(&lh[t * KLAB + k], 1u);
        }
    }

    // wave-level reduce of scalar partials (64 lanes, 8 waves)
#pragma unroll
    for (int off = 32; off > 0; off >>= 1) {
        s2   += __shfl_down(s2, off);
        sp   += __shfl_down(sp, off);
        spt  += __shfl_down(spt, off);
        sbce += __shfl_down(sbce, off);
    }
    int wave = threadIdx.x >> 6;
    if ((threadIdx.x & 63) == 0) {
        red[wave][0] = s2; red[wave][1] = sp; red[wave][2] = spt; red[wave][3] = sbce;
    }
    __syncthreads();  // red written AND all LDS histogram atomics complete

    if (threadIdx.x == 0) {
        float4 r = {0.f, 0.f, 0.f, 0.f};
#pragma unroll
        for (int w = 0; w < 8; ++w) {
            r.x += red[w][0]; r.y += red[w][1]; r.z += red[w][2]; r.w += red[w][3];
        }
        parts[blockIdx.x] = r;
    }

    // store-only flush: pack two u16 counts per u32 (per-block max 8192 < 65536)
    if (threadIdx.x < NBIN / 2) {
        unsigned int w = lh[2 * threadIdx.x] | (lh[2 * threadIdx.x + 1] << 16);
        hist1[blockIdx.x * (NBIN / 2) + threadIdx.x] = w;
    }
}

__global__ __launch_bounds__(512) void connect_fin(
    const unsigned int* __restrict__ hist1, const float4* __restrict__ parts,
    float* __restrict__ out)
{
    __shared__ float  fh[NBIN];
    __shared__ unsigned int ph[2][NBIN];  // [b-half][bin]
    __shared__ double sred[8][4];
    __shared__ float  rowmin[NLAB];
    __shared__ float  strow[NLAB];

    int tid = threadIdx.x;

    // ---- reduce packed u16 histograms: col = bin-pair, half = b-range ----
    {
        int col  = tid & 255;            // bin pair index (bins 2col, 2col+1)
        int half = tid >> 8;             // 0: blocks 0..255, 1: blocks 256..511
        unsigned int s0 = 0u, s1 = 0u;
#pragma unroll 8
        for (int b = half * 256; b < half * 256 + 256; ++b) {
            unsigned int w = hist1[b * (NBIN / 2) + col];
            s0 += w & 0xFFFFu;
            s1 += w >> 16;
        }
        ph[half][2 * col]     = s0;
        ph[half][2 * col + 1] = s1;
    }

    // ---- reduce per-block scalar partials (one per thread) ----
    double d2, dp, dpt, dbce;
    {
        float4 r = parts[tid];
        d2 = r.x; dp = r.y; dpt = r.z; dbce = r.w;
    }
#pragma unroll
    for (int off = 32; off > 0; off >>= 1) {
        d2   += __shfl_down(d2, off);
        dp   += __shfl_down(dp, off);
        dpt  += __shfl_down(dpt, off);
        dbce += __shfl_down(dbce, off);
    }
    if ((tid & 63) == 0) {
        int w = tid >> 6;
        sred[w][0] = d2; sred[w][1] = dp; sred[w][2] = dpt; sred[w][3] = dbce;
    }
    __syncthreads();

    fh[tid] = (float)(ph[0][tid] + ph[1][tid]);
    __syncthreads();

    // ---- pair matrix: one thread per (n,k) bin ----
    int n = tid >> 5;
    int k = tid & 31;

    float st = 0.f, spk = 0.f;
#pragma unroll
    for (int kk = 0; kk < KLAB; ++kk) st += fh[n * KLAB + kk];
#pragma unroll
    for (int nn = 0; nn < NLAB; ++nn) spk += fh[nn * KLAB + k];

    float I   = fh[n * KLAB + k];
    float uni = st + spk;
    float pair = 100.0f * (uni - 2.0f * I) / (float)HW_TOT
               + 1.0f - (2.0f * I + 1.0f) / (uni + 1.0f);

    float v = pair;
#pragma unroll
    for (int off = 16; off > 0; off >>= 1) v = fminf(v, __shfl_xor(v, off));

    if (k == 0) { rowmin[n] = v; strow[n] = st; }
    __syncthreads();

    if (tid == 0) {
        double S2 = 0, SP = 0, SPT = 0, SBCE = 0;
#pragma unroll
        for (int w = 0; w < 8; ++w) {
            S2 += sred[w][0]; SP += sred[w][1]; SPT += sred[w][2]; SBCE += sred[w][3];
        }
        double hw = (double)HW_TOT;
        double res = S2 / hw;                 // MSE(pred_score, 0)
        res += -SBCE / hw;                    // BCE(cls_out, t)
        double sum_t = hw - (double)strow[0]; // count(target > 0)
        res += 1.0 - (2.0 * SPT + 1.0) / (SP + sum_t + 1.0);
        float pm = 0.f;
#pragma unroll
        for (int i = 0; i < NLAB; ++i) pm += rowmin[i];
        res += (double)pm;
        out[0] = (float)(res / (double)NLAB);
    }
}

extern "C" void kernel_launch(void* const* d_in, const int* in_sizes, int n_in,
                              void* d_out, int out_size, void* d_ws, size_t ws_size,
                              hipStream_t stream) {
    const vint4*   pim = (const vint4*)d_in[0];
    const vfloat4* ps  = (const vfloat4*)d_in[1];
    const vfloat4* co  = (const vfloat4*)d_in[2];
    const vint4*   tm  = (const vint4*)d_in[3];
    float* out = (float*)d_out;

    unsigned int* hist1 = (unsigned int*)d_ws;                       // 512 KB
    float4*       parts = (float4*)((char*)d_ws + (size_t)NBLK * (NBIN / 2) * 4);

    const int nvec = HW_TOT / 4;
    connect_k1<<<NBLK, BTHR, 0, stream>>>(pim, ps, co, tm, parts, hist1, nvec);
    connect_fin<<<1, 512, 0, stream>>>(hist1, parts, out);
}

// Round 10
// 20.611 us; speedup vs baseline: 1.3987x; 1.2297x over previous
//
#include <hip/hip_runtime.h>

#define HW_TOT (2048 * 2048)
#define KLAB 32
#define NLAB 16
#define NBIN (NLAB * KLAB)   // 512
#define NBLK 256             // k1 grid: 1 block/CU, 16 waves each
#define BTHR 1024            // threads per k1 block

typedef int   vint4   __attribute__((ext_vector_type(4)));
typedef float vfloat4 __attribute__((ext_vector_type(4)));

// ws layout (every byte store-overwritten each call -> no memset):
//   [0)       u32 hist1[NBLK][NBIN/2]  256 KB  (packed u16 pairs: bins 2c,2c+1)
//   [262144)  float4 parts[NBLK]         4 KB

__global__ __launch_bounds__(BTHR) void connect_k1(
    const vint4* __restrict__ pim, const vfloat4* __restrict__ ps,
    const vfloat4* __restrict__ co, const vint4* __restrict__ tm,
    float4* __restrict__ parts, unsigned int* __restrict__ hist1, int nvec)
{
    __shared__ unsigned int lh[NBIN];
    __shared__ float red[16][4];

    if (threadIdx.x < NBIN) lh[threadIdx.x] = 0u;
    __syncthreads();

    float s2 = 0.f, sp = 0.f, spt = 0.f, sbce = 0.f;

    const int stride = gridDim.x * blockDim.x;  // 262144
    for (int i = blockIdx.x * blockDim.x + threadIdx.x; i < nvec; i += stride) {
        vint4   pv = __builtin_nontemporal_load(&pim[i]);
        vfloat4 sv = __builtin_nontemporal_load(&ps[i]);
        vfloat4 cv = __builtin_nontemporal_load(&co[i]);
        vint4   tv = __builtin_nontemporal_load(&tm[i]);

#pragma unroll
        for (int e = 0; e < 4; ++e) {
            float s = sv[e];
            float p = cv[e];
            int   t = tv[e];
            int   k = pv[e];

            s2 += s * s;
            sp += p;
            bool tb = (t > 0);
            float sel = tb ? p : (1.0f - p);
            float lg = fmaxf(__logf(sel), -100.0f);
            sbce += lg;
            if (tb) spt += p;

            atomicAdd(&lh[t * KLAB + k], 1u);
        }
    }

    // wave-level reduce of scalar partials (16 waves)
#pragma unroll
    for (int off = 32; off > 0; off >>= 1) {
        s2   += __shfl_down(s2, off);
        sp   += __shfl_down(sp, off);
        spt  += __shfl_down(spt, off);
        sbce += __shfl_down(sbce, off);
    }
    int wave = threadIdx.x >> 6;
    if ((threadIdx.x & 63) == 0) {
        red[wave][0] = s2; red[wave][1] = sp; red[wave][2] = spt; red[wave][3] = sbce;
    }
    __syncthreads();  // red written AND all LDS histogram atomics complete

    if (threadIdx.x == 0) {
        float4 r = {0.f, 0.f, 0.f, 0.f};
#pragma unroll
        for (int w = 0; w < 16; ++w) {
            r.x += red[w][0]; r.y += red[w][1]; r.z += red[w][2]; r.w += red[w][3];
        }
        parts[blockIdx.x] = r;
    }

    // store-only flush: pack two u16 counts per u32 (per-block max 16384 < 65536)
    if (threadIdx.x < NBIN / 2) {
        unsigned int w = lh[2 * threadIdx.x] | (lh[2 * threadIdx.x + 1] << 16);
        hist1[blockIdx.x * (NBIN / 2) + threadIdx.x] = w;
    }
}

__global__ __launch_bounds__(1024) void connect_fin(
    const unsigned int* __restrict__ hist1, const float4* __restrict__ parts,
    float* __restrict__ out)
{
    __shared__ unsigned int ph[4][NBIN];  // [block-chunk][bin]
    __shared__ float  fh[NBIN];
    __shared__ double sred[4][4];
    __shared__ float  rowmin[NLAB];
    __shared__ float  strow[NLAB];

    int tid = threadIdx.x;

    // ---- reduce packed u16 histograms: 4 chunks x 256 bin-pair columns ----
    {
        int col   = tid & 255;           // bin-pair (bins 2col, 2col+1)
        int chunk = tid >> 8;            // 0..3 -> blocks chunk*64 .. +64
        unsigned int s0 = 0u, s1 = 0u;
#pragma unroll 16
        for (int b = chunk * 64; b < chunk * 64 + 64; ++b) {
            unsigned int w = hist1[b * (NBIN / 2) + col];
            s0 += w & 0xFFFFu;
            s1 += w >> 16;
        }
        ph[chunk][2 * col]     = s0;
        ph[chunk][2 * col + 1] = s1;
    }

    // ---- reduce per-block scalar partials (blocks 0..255 on waves 0..3) ----
    double d2 = 0.0, dp = 0.0, dpt = 0.0, dbce = 0.0;
    if (tid < NBLK) {
        float4 r = parts[tid];
        d2 = r.x; dp = r.y; dpt = r.z; dbce = r.w;
    }
#pragma unroll
    for (int off = 32; off > 0; off >>= 1) {
        d2   += __shfl_down(d2, off);
        dp   += __shfl_down(dp, off);
        dpt  += __shfl_down(dpt, off);
        dbce += __shfl_down(dbce, off);
    }
    if (tid < NBLK && (tid & 63) == 0) {
        int w = tid >> 6;
        sred[w][0] = d2; sred[w][1] = dp; sred[w][2] = dpt; sred[w][3] = dbce;
    }
    __syncthreads();

    if (tid < NBIN)
        fh[tid] = (float)(ph[0][tid] + ph[1][tid] + ph[2][tid] + ph[3][tid]);
    __syncthreads();

    // ---- pair matrix: one thread per (n,k) bin, threads 0..511 ----
    if (tid < NBIN) {
        int n = tid >> 5;
        int k = tid & 31;

        float st = 0.f, spk = 0.f;
#pragma unroll
        for (int kk = 0; kk < KLAB; ++kk) st += fh[n * KLAB + kk];
#pragma unroll
        for (int nn = 0; nn < NLAB; ++nn) spk += fh[nn * KLAB + k];

        float I   = fh[n * KLAB + k];
        float uni = st + spk;
        float pair = 100.0f * (uni - 2.0f * I) / (float)HW_TOT
                   + 1.0f - (2.0f * I + 1.0f) / (uni + 1.0f);

        float v = pair;
#pragma unroll
        for (int off = 16; off > 0; off >>= 1) v = fminf(v, __shfl_xor(v, off));

        if (k == 0) { rowmin[n] = v; strow[n] = st; }
    }
    __syncthreads();

    if (tid == 0) {
        double S2 = 0, SP = 0, SPT = 0, SBCE = 0;
#pragma unroll
        for (int w = 0; w < 4; ++w) {
            S2 += sred[w][0]; SP += sred[w][1]; SPT += sred[w][2]; SBCE += sred[w][3];
        }
        double hw = (double)HW_TOT;
        double res = S2 / hw;                 // MSE(pred_score, 0)
        res += -SBCE / hw;                    // BCE(cls_out, t)
        double sum_t = hw - (double)strow[0]; // count(target > 0)
        res += 1.0 - (2.0 * SPT + 1.0) / (SP + sum_t + 1.0);
        float pm = 0.f;
#pragma unroll
        for (int i = 0; i < NLAB; ++i) pm += rowmin[i];
        res += (double)pm;
        out[0] = (float)(res / (double)NLAB);
    }
}

extern "C" void kernel_launch(void* const* d_in, const int* in_sizes, int n_in,
                              void* d_out, int out_size, void* d_ws, size_t ws_size,
                              hipStream_t stream) {
    const vint4*   pim = (const vint4*)d_in[0];
    const vfloat4* ps  = (const vfloat4*)d_in[1];
    const vfloat4* co  = (const vfloat4*)d_in[2];
    const vint4*   tm  = (const vint4*)d_in[3];
    float* out = (float*)d_out;

    unsigned int* hist1 = (unsigned int*)d_ws;                         // 256 KB
    float4*       parts = (float4*)((char*)d_ws + (size_t)NBLK * (NBIN / 2) * 4);

    const int nvec = HW_TOT / 4;
    connect_k1<<<NBLK, BTHR, 0, stream>>>(pim, ps, co, tm, parts, hist1, nvec);
    connect_fin<<<1, 1024, 0, stream>>>(hist1, parts, out);
}